// Round 8
// baseline (78.951 us; speedup 1.0000x reference)
//
#include <hip/hip_runtime.h>

#define D 128
#define B 256
#define WMAX 64
#define SPILL_MAX 8192
#define NPART 8   // XCD count on MI355X; blockIdx % 8 ~ XCD (perf heuristic only)

typedef float vfloat4 __attribute__((ext_vector_type(4)));

// ---------------------------------------------------------------------------
// GCN message passing, ELL + bf16-gather + XCD-partitioned build:
//   prep : cursor=0, out2=x (NT), xb=bf16(x)
//   place: 8 block-groups (one per XCD); group p scans ALL edges as int4
//          chunks (coalesced row+col), keeps dests in [n*p/8, n*(p+1)/8),
//          4 independent cursor atomics in flight per thread.
//   agg  : same partition ranges; 32 lanes/node, 8B bf16 gather, x4 unroll.
//   spill edges (deg > WMAX, normally none) folded into agg.
// Fallback (small ws): round-4 CSR-pairs pipeline.
// ---------------------------------------------------------------------------

__device__ __forceinline__ unsigned short f2bf(float f) {   // RTNE f32->bf16
    unsigned u = __float_as_uint(f);
    u = u + 0x7FFFu + ((u >> 16) & 1u);
    return (unsigned short)(u >> 16);
}

__device__ __forceinline__ vfloat4 bf2f4(uint2 v) {
    vfloat4 r;
    r.x = __uint_as_float(v.x << 16);
    r.y = __uint_as_float(v.x & 0xffff0000u);
    r.z = __uint_as_float(v.y << 16);
    r.w = __uint_as_float(v.y & 0xffff0000u);
    return r;
}

__global__ void k_prep(const float* __restrict__ x, float* __restrict__ out2,
                       uint2* __restrict__ xb, int* __restrict__ cursor,
                       int* __restrict__ spillCnt, int n) {
    int gid = blockIdx.x * blockDim.x + threadIdx.x;
    if (gid == 0) *spillCnt = 0;
    if (gid < n) cursor[gid] = 0;
    if (gid >= n * 32) return;
    vfloat4 xv = reinterpret_cast<const vfloat4*>(x)[gid];
    __builtin_nontemporal_store(xv, reinterpret_cast<vfloat4*>(out2) + gid);
    uint2 b;
    b.x = (unsigned)f2bf(xv.x) | ((unsigned)f2bf(xv.y) << 16);
    b.y = (unsigned)f2bf(xv.z) | ((unsigned)f2bf(xv.w) << 16);
    xb[gid] = b;
}

// Group p (= blockIdx%8) scans all edges as int4 chunks; keeps dests in its
// node range. All global reads coalesced; 4 independent atomics in flight.
__global__ void k_place_ell(const int* __restrict__ row, const int* __restrict__ col,
                            int* __restrict__ cursor, int* __restrict__ ssrc,
                            int2* __restrict__ spill, int* __restrict__ spillCnt,
                            int e, int n) {
    int p  = blockIdx.x & (NPART - 1);
    int bg = blockIdx.x >> 3;                       // block index within group
    int tg = bg * blockDim.x + threadIdx.x;         // thread index within group
    int T  = (gridDim.x >> 3) * blockDim.x;         // threads per group
    int lo = (int)((long long)n * p / NPART);
    int hi = (int)((long long)n * (p + 1) / NPART);

    const int4* col4 = reinterpret_cast<const int4*>(col);
    const int4* row4 = reinterpret_cast<const int4*>(row);
    int e4 = e >> 2;

    for (int i = tg; i < e4; i += T) {
        int4 c4 = col4[i];
        int4 r4 = row4[i];
        int cs[4] = {c4.x, c4.y, c4.z, c4.w};
        int rs[4] = {r4.x, r4.y, r4.z, r4.w};
        int pos[4];
#pragma unroll
        for (int u = 0; u < 4; ++u) {
            bool keep = (cs[u] >= lo) & (cs[u] < hi);
            pos[u] = keep ? atomicAdd(&cursor[cs[u]], 1) : -1;
        }
#pragma unroll
        for (int u = 0; u < 4; ++u) {
            if (pos[u] < 0) continue;
            if (pos[u] < WMAX) {
                ssrc[cs[u] * WMAX + pos[u]] = rs[u];
            } else {
                int s = atomicAdd(spillCnt, 1);
                if (s < SPILL_MAX) spill[s] = make_int2(rs[u], cs[u]);
            }
        }
    }
    // tail (e % 4 != 0)
    for (int i = (e4 << 2) + tg; i < e; i += T) {
        int c = col[i];
        if (c < lo || c >= hi) continue;
        int r = row[i];
        int pos = atomicAdd(&cursor[c], 1);
        if (pos < WMAX) {
            ssrc[c * WMAX + pos] = r;
        } else {
            int s = atomicAdd(spillCnt, 1);
            if (s < SPILL_MAX) spill[s] = make_int2(r, c);
        }
    }
}

// 32 lanes per node, 8B bf16 gather per lane, x4 unrolled; spill folded in.
// Partition mapping EXACTLY matches k_place_ell's [n*p/8, n*(p+1)/8) ranges.
__global__ void k_agg_ell(const uint2* __restrict__ xb, const float* __restrict__ bias,
                          const int* __restrict__ cursor, const int* __restrict__ ssrc,
                          const int2* __restrict__ spill, const int* __restrict__ spillCnt,
                          float* __restrict__ out, int n) {
    int p  = blockIdx.x & (NPART - 1);
    int bg = blockIdx.x >> 3;                        // block index within group
    int lo = (int)((long long)n * p / NPART);
    int hi = (int)((long long)n * (p + 1) / NPART);
    int node = lo + bg * 8 + (threadIdx.x >> 5);     // 8 nodes per block
    if (node >= hi) return;
    int q = threadIdx.x & 31;

    int cnt = cursor[node];
    int m   = min(cnt, WMAX);
    const int* sp = ssrc + node * WMAX;

    vfloat4 a0 = {0.f, 0.f, 0.f, 0.f};
    vfloat4 a1 = a0, a2 = a0, a3 = a0;

    int j = 0;
    for (; j + 4 <= m; j += 4) {
        int r0 = sp[j + 0], r1 = sp[j + 1], r2 = sp[j + 2], r3 = sp[j + 3];
        uint2 v0 = xb[(size_t)r0 * 32 + q];
        uint2 v1 = xb[(size_t)r1 * 32 + q];
        uint2 v2 = xb[(size_t)r2 * 32 + q];
        uint2 v3 = xb[(size_t)r3 * 32 + q];
        float w0 = rsqrtf((float)cursor[r0] + 1.0f);
        float w1 = rsqrtf((float)cursor[r1] + 1.0f);
        float w2 = rsqrtf((float)cursor[r2] + 1.0f);
        float w3 = rsqrtf((float)cursor[r3] + 1.0f);
        a0 += w0 * bf2f4(v0);
        a1 += w1 * bf2f4(v1);
        a2 += w2 * bf2f4(v2);
        a3 += w3 * bf2f4(v3);
    }
    for (; j < m; ++j) {
        int r = sp[j];
        uint2 v = xb[(size_t)r * 32 + q];
        float w = rsqrtf((float)cursor[r] + 1.0f);
        a0 += w * bf2f4(v);
    }

    // Overflow edges (normally zero): scan the tiny spill list.
    if (cnt > WMAX) {
        int sc = min(*spillCnt, SPILL_MAX);
        for (int s = 0; s < sc; ++s) {
            int2 pr = spill[s];
            if (pr.y == node) {
                float w = rsqrtf((float)cursor[pr.x] + 1.0f);
                a0 += w * bf2f4(xb[(size_t)pr.x * 32 + q]);
            }
        }
    }

    float dc = rsqrtf((float)cnt + 1.0f);
    vfloat4 xc = bf2f4(xb[(size_t)node * 32 + q]);
    vfloat4 bv = reinterpret_cast<const vfloat4*>(bias)[q];
    vfloat4 ov = bv + dc * (a0 + a1 + a2 + a3 + dc * xc);

    __builtin_nontemporal_store(ov, reinterpret_cast<vfloat4*>(out) + (size_t)node * 32 + q);
}

// ======================= fallback: round-4 CSR pipeline =======================

__global__ void k_zero(int* __restrict__ degInt, int n) {
    int i = blockIdx.x * blockDim.x + threadIdx.x;
    if (i < n) degInt[i] = 0;
}

__global__ void k_count(const int* __restrict__ col, int* __restrict__ degInt, int e) {
    int i = blockIdx.x * blockDim.x + threadIdx.x;
    if (i < e) atomicAdd(&degInt[col[i]], 1);
}

__global__ void k_scan1(const int* __restrict__ degInt, int* __restrict__ off,
                        int* __restrict__ bsum, int n) {
    __shared__ int sm[B];
    int i = blockIdx.x * B + threadIdx.x;
    int v = (i < n) ? degInt[i] : 0;
    sm[threadIdx.x] = v;
    __syncthreads();
    for (int s = 1; s < B; s <<= 1) {
        int t = (threadIdx.x >= (unsigned)s) ? sm[threadIdx.x - s] : 0;
        __syncthreads();
        sm[threadIdx.x] += t;
        __syncthreads();
    }
    if (i < n) off[i] = sm[threadIdx.x] - v;
    if (threadIdx.x == B - 1) bsum[blockIdx.x] = sm[B - 1];
}

__global__ void k_scan2(int* __restrict__ bsum, int nb) {
    __shared__ int sm[B];
    int v = (threadIdx.x < (unsigned)nb) ? bsum[threadIdx.x] : 0;
    sm[threadIdx.x] = v;
    __syncthreads();
    for (int s = 1; s < B; s <<= 1) {
        int t = (threadIdx.x >= (unsigned)s) ? sm[threadIdx.x - s] : 0;
        __syncthreads();
        sm[threadIdx.x] += t;
        __syncthreads();
    }
    if (threadIdx.x < (unsigned)nb) bsum[threadIdx.x] = sm[threadIdx.x] - v;
}

__global__ void k_scan3(int* __restrict__ off, const int* __restrict__ bsum,
                        const int* __restrict__ degInt, float* __restrict__ dis,
                        int* __restrict__ cursor, int n, int e) {
    int i = blockIdx.x * B + threadIdx.x;
    if (i < n) {
        int o = off[i] + bsum[blockIdx.x];
        off[i] = o;
        cursor[i] = o;
        dis[i] = rsqrtf((float)degInt[i] + 1.0f);
    }
    if (i == 0) off[n] = e;
}

__global__ void k_place_pairs(const int* __restrict__ row, const int* __restrict__ col,
                              const float* __restrict__ dis, int* __restrict__ cursor,
                              int2* __restrict__ pairs, int e) {
    int i = blockIdx.x * blockDim.x + threadIdx.x;
    if (i >= e) return;
    int r = row[i];
    int c = col[i];
    float w = dis[r];
    int pos = atomicAdd(&cursor[c], 1);
    pairs[pos] = make_int2(r, __float_as_int(w));
}

__global__ void k_aggregate_pairs(const float* __restrict__ x, const float* __restrict__ bias,
                                  const float* __restrict__ dis, const int* __restrict__ off,
                                  const int2* __restrict__ pairs, float* __restrict__ out,
                                  float* __restrict__ out2, int n) {
    int gid = blockIdx.x * blockDim.x + threadIdx.x;
    if (gid >= n * 32) return;
    int node = gid >> 5;
    int q    = gid & 31;
    const vfloat4* x4 = reinterpret_cast<const vfloat4*>(x);
    int j   = off[node];
    int end = off[node + 1];
    vfloat4 a0 = {0.f, 0.f, 0.f, 0.f};
    vfloat4 a1 = a0, a2 = a0, a3 = a0;
    for (; j + 4 <= end; j += 4) {
        int2 p0 = pairs[j + 0];
        int2 p1 = pairs[j + 1];
        int2 p2 = pairs[j + 2];
        int2 p3 = pairs[j + 3];
        vfloat4 v0 = x4[(size_t)p0.x * 32 + q];
        vfloat4 v1 = x4[(size_t)p1.x * 32 + q];
        vfloat4 v2 = x4[(size_t)p2.x * 32 + q];
        vfloat4 v3 = x4[(size_t)p3.x * 32 + q];
        a0 += __int_as_float(p0.y) * v0;
        a1 += __int_as_float(p1.y) * v1;
        a2 += __int_as_float(p2.y) * v2;
        a3 += __int_as_float(p3.y) * v3;
    }
    for (; j < end; ++j) {
        int2 p = pairs[j];
        a0 += __int_as_float(p.y) * x4[(size_t)p.x * 32 + q];
    }
    float dc = dis[node];
    vfloat4 xc = x4[(size_t)node * 32 + q];
    vfloat4 bv = reinterpret_cast<const vfloat4*>(bias)[q];
    vfloat4 ov = bv + dc * (a0 + a1 + a2 + a3 + dc * xc);
    __builtin_nontemporal_store(ov, reinterpret_cast<vfloat4*>(out)  + (size_t)node * 32 + q);
    __builtin_nontemporal_store(xc, reinterpret_cast<vfloat4*>(out2) + (size_t)node * 32 + q);
}

// =============================================================================

extern "C" void kernel_launch(void* const* d_in, const int* in_sizes, int n_in,
                              void* d_out, int out_size, void* d_ws, size_t ws_size,
                              hipStream_t stream) {
    const float* x    = (const float*)d_in[0];
    const int*   idx  = (const int*)d_in[1];   // [2, E]
    const float* bias = (const float*)d_in[2];

    const int n = in_sizes[0] / D;             // 50000
    const int e = in_sizes[1] / 2;             // 600000

    const int* row = idx;                      // sources
    const int* col = idx + e;                  // destinations

    float* out  = (float*)d_out;                     // [n, 128]
    float* out2 = (float*)d_out + (size_t)n * D;     // init_embeds

    const int nbN = (n + B - 1) / B;
    const int nbE = (e + B - 1) / B;
    const int aggB = (n * 32 + B - 1) / B;

    // ---- ELL + bf16 layout ----
    char* p0 = (char*)d_ws;
    int*  cursor  = (int*)p0;                        p0 += (size_t)n * 4;
    int*  spillCnt= (int*)p0;                        p0 += 16;
    int2* spill   = (int2*)p0;                       p0 += (size_t)SPILL_MAX * 8;
    p0 = (char*)(((uintptr_t)p0 + 15) & ~(uintptr_t)15);
    uint2* xb     = (uint2*)p0;                      p0 += (size_t)n * 32 * 8;   // bf16 x
    int*  ssrc    = (int*)p0;                        p0 += (size_t)n * WMAX * 4;
    size_t need_ell = (size_t)(p0 - (char*)d_ws);

    if (ws_size >= need_ell) {
        const int plB = 2048;   // 8 XCD groups x 256 blocks, all co-resident
        // agg: per-partition block count covering ceil(maxPartSize/8) nodes
        int maxPart = 0;
        for (int p = 0; p < NPART; ++p) {
            int lo = (int)((long long)n * p / NPART);
            int hi = (int)((long long)n * (p + 1) / NPART);
            if (hi - lo > maxPart) maxPart = hi - lo;
        }
        const int bpg = (maxPart + 7) / 8;
        const int agB = bpg * NPART;
        k_prep     <<<aggB, B, 0, stream>>>(x, out2, xb, cursor, spillCnt, n);
        k_place_ell<<<plB,  B, 0, stream>>>(row, col, cursor, ssrc, spill, spillCnt, e, n);
        k_agg_ell  <<<agB,  B, 0, stream>>>(xb, bias, cursor, ssrc, spill, spillCnt, out, n);
        return;
    }

    // ---- fallback: round-4 CSR pipeline ----
    char* p = (char*)d_ws;
    int*   degInt = (int*)p;            p += (size_t)n * 4;
    int*   cur2   = (int*)p;            p += (size_t)n * 4;
    int*   off    = (int*)p;            p += (size_t)(n + 1) * 4;
    int*   bsum   = (int*)p;            p += 256 * 4;
    float* dis    = (float*)p;          p += (size_t)n * 4;
    p = (char*)(((uintptr_t)p + 15) & ~(uintptr_t)15);
    int2*  pairs  = (int2*)p;

    k_zero <<<nbN, B, 0, stream>>>(degInt, n);
    k_count<<<nbE, B, 0, stream>>>(col, degInt, e);
    k_scan1<<<nbN, B, 0, stream>>>(degInt, off, bsum, n);
    k_scan2<<<1,   B, 0, stream>>>(bsum, nbN);
    k_scan3<<<nbN, B, 0, stream>>>(off, bsum, degInt, dis, cur2, n, e);
    k_place_pairs<<<nbE, B, 0, stream>>>(row, col, dis, cur2, pairs, e);
    k_aggregate_pairs<<<aggB, B, 0, stream>>>(x, bias, dis, off, pairs, out, out2, n);
}